// Round 1
// baseline (719.233 us; speedup 1.0000x reference)
//
#include <hip/hip_runtime.h>
#include <hip/hip_bf16.h>
#include <cstdint>
#include <cstddef>

#define S 4096
#define D 1024
#define H 16
#define HD 64
#define BATCH 2
#define M_TOK 8192   // BATCH*S
#define K2 2048

typedef short short8 __attribute__((ext_vector_type(8)));
typedef __bf16 bf16x8 __attribute__((ext_vector_type(8)));
typedef float f32x4 __attribute__((ext_vector_type(4)));

static __device__ __forceinline__ ushort f2bf(float f) {
  union { float f; uint32_t u; } v; v.f = f;
  uint32_t u = v.u + 0x7FFFu + ((v.u >> 16) & 1u);
  return (ushort)(u >> 16);
}
static __device__ __forceinline__ float bf2f(ushort h) {
  union { uint32_t u; float f; } v; v.u = ((uint32_t)h) << 16; return v.f;
}

// ---------------- prep: x -> [hi|lo] bf16 concat; W -> sign(W) bf16 ----------------
__global__ void prep_x(const float* __restrict__ x, ushort* __restrict__ xcat) {
  int i = blockIdx.x * blockDim.x + threadIdx.x;
  const int total = M_TOK * D;
  for (; i < total; i += gridDim.x * blockDim.x) {
    int row = i >> 10, col = i & 1023;
    float v = x[i];
    ushort hi = f2bf(v);
    float r = v - bf2f(hi);
    xcat[row * K2 + col] = hi;
    xcat[row * K2 + 1024 + col] = f2bf(r);
  }
}

__global__ void prep_w(const float* __restrict__ wq, const float* __restrict__ wk,
                       const float* __restrict__ wv, const float* __restrict__ wo,
                       ushort* __restrict__ bq, ushort* __restrict__ bk,
                       ushort* __restrict__ bv, ushort* __restrict__ bw) {
  int i = blockIdx.x * blockDim.x + threadIdx.x;
  const int total = D * D;
  for (; i < total; i += gridDim.x * blockDim.x) {
    float a;
    a = wq[i]; bq[i] = a > 0.f ? 0x3F80 : (a < 0.f ? 0xBF80 : 0);
    a = wk[i]; bk[i] = a > 0.f ? 0x3F80 : (a < 0.f ? 0xBF80 : 0);
    a = wv[i]; bv[i] = a > 0.f ? 0x3F80 : (a < 0.f ? 0xBF80 : 0);
    a = wo[i]; bw[i] = a > 0.f ? 0x3F80 : (a < 0.f ? 0xBF80 : 0);
  }
}

// ---------------- GEMM: C = A (MxK, row-major) * B^T (B is [N][1024], k wraps &kmask) ----------------
// EPI 0: write bf16 hi+lo into [b,h,n,hd] (Q/K).  EPI 1: write bf16 into [b,h,hd,n] (V^T).
// EPI 2: write fp32 + bias into [row][col] (final output).
template<int EPI>
__global__ __launch_bounds__(256) void gemm128(
    const ushort* __restrict__ A, const ushort* __restrict__ Bw,
    int K, int kmask,
    ushort* __restrict__ o0, ushort* __restrict__ o1,
    float* __restrict__ of, const float* __restrict__ bias)
{
  __shared__ ushort smA[128 * 48];
  __shared__ ushort smB[128 * 48];
  const int tid = threadIdx.x;
  const int l = tid & 63;
  const int w = tid >> 6;
  const int wm = w >> 1, wn = w & 1;
  const int bm = blockIdx.x >> 3, bn = blockIdx.x & 7;

  f32x4 acc[4][4] = {};

  for (int k0 = 0; k0 < K; k0 += 32) {
    __syncthreads();
#pragma unroll
    for (int p = 0; p < 2; ++p) {
      int row = p * 64 + (tid >> 2);
      int c8 = (tid & 3) * 8;
      *(short8*)&smA[row * 48 + c8] =
          *(const short8*)&A[(size_t)(bm * 128 + row) * K + k0 + c8];
      *(short8*)&smB[row * 48 + c8] =
          *(const short8*)&Bw[(size_t)(bn * 128 + row) * (size_t)(kmask + 1) + ((k0 + c8) & kmask)];
    }
    __syncthreads();
    bf16x8 af[4], bfr[4];
#pragma unroll
    for (int m = 0; m < 4; ++m)
      af[m] = *(const bf16x8*)&smA[(wm * 64 + m * 16 + (l & 15)) * 48 + (l >> 4) * 8];
#pragma unroll
    for (int n = 0; n < 4; ++n)
      bfr[n] = *(const bf16x8*)&smB[(wn * 64 + n * 16 + (l & 15)) * 48 + (l >> 4) * 8];
#pragma unroll
    for (int m = 0; m < 4; ++m)
#pragma unroll
      for (int n = 0; n < 4; ++n)
        acc[m][n] = __builtin_amdgcn_mfma_f32_16x16x32_bf16(af[m], bfr[n], acc[m][n], 0, 0, 0);
  }

#pragma unroll
  for (int m = 0; m < 4; ++m) {
    int rowb = wm * 64 + m * 16 + (l >> 4) * 4;
#pragma unroll
    for (int n = 0; n < 4; ++n) {
      int colg = bn * 128 + wn * 64 + n * 16 + (l & 15);
#pragma unroll
      for (int r = 0; r < 4; ++r) {
        int rowg = bm * 128 + rowb + r;
        float v = acc[m][n][r];
        if (EPI == 2) {
          of[(size_t)rowg * D + colg] = v + bias[colg];
        } else {
          int bi = rowg >> 12;
          int ntok = rowg & 4095;
          int h = colg >> 6, hd = colg & 63;
          size_t bh = (size_t)(bi * H + h);
          if (EPI == 0) {
            size_t off = bh * (S * HD) + (size_t)ntok * HD + hd;
            ushort hiv = f2bf(v);
            o0[off] = hiv;
            o1[off] = f2bf(v - bf2f(hiv));
          } else {
            size_t off = bh * (S * HD) + (size_t)hd * S + ntok;
            o0[off] = f2bf(v);
          }
        }
      }
    }
  }
}

// ---------------- flash attention (causal), 3-term hi/lo scores ----------------
__global__ __launch_bounds__(256) void flash(
    const ushort* __restrict__ qhi, const ushort* __restrict__ qlo,
    const ushort* __restrict__ khi, const ushort* __restrict__ klo,
    const ushort* __restrict__ vt, ushort* __restrict__ ctx)
{
  __shared__ ushort smKhi[64 * 72];
  __shared__ ushort smKlo[64 * 72];
  __shared__ ushort smVT[64 * 72];
  __shared__ ushort smP[4][16 * 72];

  const int tid = threadIdx.x;
  const int l = tid & 63;
  const int w = tid >> 6;
  const int bh = blockIdx.x >> 6;   // 0..31
  const int qt = blockIdx.x & 63;   // q tile of 64 rows
  const size_t qkbase = (size_t)bh * S * HD;

  bf16x8 aqh[2], aql[2];
  {
    int qrow = qt * 64 + w * 16 + (l & 15);
    size_t base = qkbase + (size_t)qrow * HD + (l >> 4) * 8;
    aqh[0] = *(const bf16x8*)&qhi[base];
    aqh[1] = *(const bf16x8*)&qhi[base + 32];
    aql[0] = *(const bf16x8*)&qlo[base];
    aql[1] = *(const bf16x8*)&qlo[base + 32];
  }

  float mrun[4], lrun[4];
  f32x4 oacc[4] = {};
#pragma unroll
  for (int r = 0; r < 4; ++r) { mrun[r] = -1e30f; lrun[r] = 0.f; }

  for (int kv = 0; kv <= qt; ++kv) {
    __syncthreads();
    {
      const ushort* kh  = khi + qkbase + (size_t)kv * 64 * HD;
      const ushort* klp = klo + qkbase + (size_t)kv * 64 * HD;
      const ushort* vtp = vt  + qkbase + (size_t)kv * 64;
#pragma unroll
      for (int p = 0; p < 2; ++p) {
        int rr = p * 32 + (tid >> 3);
        int cc = (tid & 7) * 8;
        *(short8*)&smKhi[rr * 72 + cc] = *(const short8*)&kh[rr * HD + cc];
        *(short8*)&smKlo[rr * 72 + cc] = *(const short8*)&klp[rr * HD + cc];
        *(short8*)&smVT[rr * 72 + cc]  = *(const short8*)&vtp[(size_t)rr * S + cc];
      }
    }
    __syncthreads();

    f32x4 sc[4];
#pragma unroll
    for (int t = 0; t < 4; ++t) {
      f32x4 a = {};
#pragma unroll
      for (int c = 0; c < 2; ++c) {
        bf16x8 kH = *(const bf16x8*)&smKhi[(t * 16 + (l & 15)) * 72 + c * 32 + (l >> 4) * 8];
        bf16x8 kL = *(const bf16x8*)&smKlo[(t * 16 + (l & 15)) * 72 + c * 32 + (l >> 4) * 8];
        a = __builtin_amdgcn_mfma_f32_16x16x32_bf16(aqh[c], kH, a, 0, 0, 0);
        a = __builtin_amdgcn_mfma_f32_16x16x32_bf16(aqh[c], kL, a, 0, 0, 0);
        a = __builtin_amdgcn_mfma_f32_16x16x32_bf16(aql[c], kH, a, 0, 0, 0);
      }
      sc[t] = a;
    }

    const bool diag = (kv == qt);
#pragma unroll
    for (int t = 0; t < 4; ++t)
#pragma unroll
      for (int r = 0; r < 4; ++r) {
        float s = sc[t][r] * 0.125f;
        if (diag) {
          int qi = w * 16 + (l >> 4) * 4 + r;
          int kj = t * 16 + (l & 15);
          if (kj > qi) s = -1e30f;
        }
        sc[t][r] = s;
      }

#pragma unroll
    for (int r = 0; r < 4; ++r) {
      float mx = fmaxf(fmaxf(sc[0][r], sc[1][r]), fmaxf(sc[2][r], sc[3][r]));
#pragma unroll
      for (int off = 8; off >= 1; off >>= 1)
        mx = fmaxf(mx, __shfl_xor(mx, off, 16));
      float mnew = fmaxf(mrun[r], mx);
      float scal = __expf(mrun[r] - mnew);
      mrun[r] = mnew;
      float ps = 0.f;
#pragma unroll
      for (int t = 0; t < 4; ++t) {
        float p = __expf(sc[t][r] - mnew);
        sc[t][r] = p;
        ps += p;
      }
#pragma unroll
      for (int off = 8; off >= 1; off >>= 1)
        ps += __shfl_xor(ps, off, 16);
      lrun[r] = lrun[r] * scal + ps;
#pragma unroll
      for (int dt = 0; dt < 4; ++dt) oacc[dt][r] *= scal;
    }

#pragma unroll
    for (int r = 0; r < 4; ++r)
#pragma unroll
      for (int t = 0; t < 4; ++t)
        smP[w][((l >> 4) * 4 + r) * 72 + t * 16 + (l & 15)] = f2bf(sc[t][r]);

    __syncthreads();

#pragma unroll
    for (int c = 0; c < 2; ++c) {
      bf16x8 ap = *(const bf16x8*)&smP[w][(l & 15) * 72 + c * 32 + (l >> 4) * 8];
#pragma unroll
      for (int dt = 0; dt < 4; ++dt) {
        bf16x8 bv = *(const bf16x8*)&smVT[(dt * 16 + (l & 15)) * 72 + c * 32 + (l >> 4) * 8];
        oacc[dt] = __builtin_amdgcn_mfma_f32_16x16x32_bf16(ap, bv, oacc[dt], 0, 0, 0);
      }
    }
  }

  const int b = bh >> 4, h = bh & 15;
#pragma unroll
  for (int dt = 0; dt < 4; ++dt)
#pragma unroll
    for (int r = 0; r < 4; ++r) {
      int tok = qt * 64 + w * 16 + (l >> 4) * 4 + r;
      int col = h * HD + dt * 16 + (l & 15);
      float o = oacc[dt][r] / lrun[r];
      ctx[(size_t)(b * S + tok) * D + col] = f2bf(o);
    }
}

extern "C" void kernel_launch(void* const* d_in, const int* in_sizes, int n_in,
                              void* d_out, int out_size, void* d_ws, size_t ws_size,
                              hipStream_t stream) {
  const float* x  = (const float*)d_in[0];
  const float* Wq = (const float*)d_in[1];
  const float* Wk = (const float*)d_in[2];
  const float* Wv = (const float*)d_in[3];
  const float* Wo = (const float*)d_in[4];
  const float* bo = (const float*)d_in[5];
  float* out = (float*)d_out;

  if (ws_size < (size_t)120 * 1024 * 1024) return;  // signature: absmax == max|ref|

  char* ws = (char*)d_ws;
  const size_t MB = 1024 * 1024;
  ushort* xcat = (ushort*)(ws);              // 32MB, later aliased as ctx
  ushort* ctx  = (ushort*)(ws);
  ushort* wqb  = (ushort*)(ws + 32 * MB);    // 2MB
  ushort* wkb  = (ushort*)(ws + 34 * MB);
  ushort* wvb  = (ushort*)(ws + 36 * MB);
  ushort* wob  = (ushort*)(ws + 38 * MB);
  ushort* qhi  = (ushort*)(ws + 40 * MB);    // 16MB each
  ushort* qlo  = (ushort*)(ws + 56 * MB);
  ushort* khi  = (ushort*)(ws + 72 * MB);
  ushort* klo  = (ushort*)(ws + 88 * MB);
  ushort* vt   = (ushort*)(ws + 104 * MB);

  prep_x<<<2048, 256, 0, stream>>>(x, xcat);
  prep_w<<<1024, 256, 0, stream>>>(Wq, Wk, Wv, Wo, wqb, wkb, wvb, wob);

  gemm128<0><<<512, 256, 0, stream>>>(xcat, wqb, K2, 1023, qhi, qlo, nullptr, nullptr);
  gemm128<0><<<512, 256, 0, stream>>>(xcat, wkb, K2, 1023, khi, klo, nullptr, nullptr);
  gemm128<1><<<512, 256, 0, stream>>>(xcat, wvb, K2, 1023, vt, nullptr, nullptr, nullptr);

  flash<<<BATCH * H * (S / 64), 256, 0, stream>>>(qhi, qlo, khi, klo, vt, ctx);

  gemm128<2><<<512, 256, 0, stream>>>(ctx, wob, D, 1023, nullptr, nullptr, out, bo);
}

// Round 2
// 401.764 us; speedup vs baseline: 1.7902x; 1.7902x over previous
//
#include <hip/hip_runtime.h>
#include <hip/hip_bf16.h>
#include <cstdint>
#include <cstddef>

#define S 4096
#define D 1024
#define H 16
#define HD 64
#define BATCH 2
#define M_TOK 8192   // BATCH*S
#define K2 2048

typedef short short8 __attribute__((ext_vector_type(8)));
typedef __bf16 bf16x8 __attribute__((ext_vector_type(8)));
typedef float f32x4 __attribute__((ext_vector_type(4)));

static __device__ __forceinline__ ushort f2bf(float f) {
  union { float f; uint32_t u; } v; v.f = f;
  uint32_t u = v.u + 0x7FFFu + ((v.u >> 16) & 1u);
  return (ushort)(u >> 16);
}
static __device__ __forceinline__ float bf2f(ushort h) {
  union { uint32_t u; float f; } v; v.u = ((uint32_t)h) << 16; return v.f;
}
static __device__ __forceinline__ uint32_t cvtpk(float lo, float hi) {
  uint32_t r;
  asm("v_cvt_pk_bf16_f32 %0, %1, %2" : "=v"(r) : "v"(lo), "v"(hi));
  return r;
}
static __device__ __forceinline__ float vexp2(float x) {
  float r;
  asm("v_exp_f32 %0, %1" : "=v"(r) : "v"(x));
  return r;
}
static __device__ __forceinline__ bf16x8 pack4(uint32_t a, uint32_t b, uint32_t c, uint32_t d) {
  union { uint32_t u[4]; bf16x8 v; } z;
  z.u[0] = a; z.u[1] = b; z.u[2] = c; z.u[3] = d;
  return z.v;
}

// ---------------- prep: x -> [hi|lo] bf16 concat; W -> sign(W) bf16 ----------------
__global__ void prep_x(const float* __restrict__ x, ushort* __restrict__ xcat) {
  int i = blockIdx.x * blockDim.x + threadIdx.x;
  const int total = M_TOK * D;
  for (; i < total; i += gridDim.x * blockDim.x) {
    int row = i >> 10, col = i & 1023;
    float v = x[i];
    ushort hi = f2bf(v);
    float r = v - bf2f(hi);
    xcat[row * K2 + col] = hi;
    xcat[row * K2 + 1024 + col] = f2bf(r);
  }
}

__global__ void prep_w(const float* __restrict__ wq, const float* __restrict__ wk,
                       const float* __restrict__ wv, const float* __restrict__ wo,
                       ushort* __restrict__ bq, ushort* __restrict__ bk,
                       ushort* __restrict__ bv, ushort* __restrict__ bw) {
  int i = blockIdx.x * blockDim.x + threadIdx.x;
  const int total = D * D;
  for (; i < total; i += gridDim.x * blockDim.x) {
    float a;
    a = wq[i]; bq[i] = a > 0.f ? 0x3F80 : (a < 0.f ? 0xBF80 : 0);
    a = wk[i]; bk[i] = a > 0.f ? 0x3F80 : (a < 0.f ? 0xBF80 : 0);
    a = wv[i]; bv[i] = a > 0.f ? 0x3F80 : (a < 0.f ? 0xBF80 : 0);
    a = wo[i]; bw[i] = a > 0.f ? 0x3F80 : (a < 0.f ? 0xBF80 : 0);
  }
}

// ---------------- GEMM: C = A (MxK, row-major) * B^T (B is [N][1024], k wraps &kmask) ----------------
template<int EPI>
__global__ __launch_bounds__(256) void gemm128(
    const ushort* __restrict__ A, const ushort* __restrict__ Bw,
    int K, int kmask,
    ushort* __restrict__ o0, ushort* __restrict__ o1,
    float* __restrict__ of, const float* __restrict__ bias)
{
  __shared__ ushort smA[128 * 48];
  __shared__ ushort smB[128 * 48];
  const int tid = threadIdx.x;
  const int l = tid & 63;
  const int w = tid >> 6;
  const int wm = w >> 1, wn = w & 1;
  const int bm = blockIdx.x >> 3, bn = blockIdx.x & 7;

  f32x4 acc[4][4] = {};

  for (int k0 = 0; k0 < K; k0 += 32) {
    __syncthreads();
#pragma unroll
    for (int p = 0; p < 2; ++p) {
      int row = p * 64 + (tid >> 2);
      int c8 = (tid & 3) * 8;
      *(short8*)&smA[row * 48 + c8] =
          *(const short8*)&A[(size_t)(bm * 128 + row) * K + k0 + c8];
      *(short8*)&smB[row * 48 + c8] =
          *(const short8*)&Bw[(size_t)(bn * 128 + row) * (size_t)(kmask + 1) + ((k0 + c8) & kmask)];
    }
    __syncthreads();
    bf16x8 af[4], bfr[4];
#pragma unroll
    for (int m = 0; m < 4; ++m)
      af[m] = *(const bf16x8*)&smA[(wm * 64 + m * 16 + (l & 15)) * 48 + (l >> 4) * 8];
#pragma unroll
    for (int n = 0; n < 4; ++n)
      bfr[n] = *(const bf16x8*)&smB[(wn * 64 + n * 16 + (l & 15)) * 48 + (l >> 4) * 8];
#pragma unroll
    for (int m = 0; m < 4; ++m)
#pragma unroll
      for (int n = 0; n < 4; ++n)
        acc[m][n] = __builtin_amdgcn_mfma_f32_16x16x32_bf16(af[m], bfr[n], acc[m][n], 0, 0, 0);
  }

#pragma unroll
  for (int m = 0; m < 4; ++m) {
    int rowb = wm * 64 + m * 16 + (l >> 4) * 4;
#pragma unroll
    for (int n = 0; n < 4; ++n) {
      int colg = bn * 128 + wn * 64 + n * 16 + (l & 15);
#pragma unroll
      for (int r = 0; r < 4; ++r) {
        int rowg = bm * 128 + rowb + r;
        float v = acc[m][n][r];
        if (EPI == 2) {
          of[(size_t)rowg * D + colg] = v + bias[colg];
        } else {
          int bi = rowg >> 12;
          int ntok = rowg & 4095;
          int h = colg >> 6, hd = colg & 63;
          size_t bh = (size_t)(bi * H + h);
          if (EPI == 0) {
            size_t off = bh * (S * HD) + (size_t)ntok * HD + hd;
            ushort hiv = f2bf(v);
            o0[off] = hiv;
            o1[off] = f2bf(v - bf2f(hiv));
          } else {
            size_t off = bh * (S * HD) + (size_t)hd * S + ntok;
            o0[off] = f2bf(v);
          }
        }
      }
    }
  }
}

// ---------------- flash attention v2: swapped QK^T, in-register softmax, no P LDS ----------------
// Block: 128 q-rows (4 waves x 32), KV tile 64. Score layout (swapped): lane holds
// S[k = t*16 + 4*g + r][q = x] for g=l>>4, x=l&15. Softmax lane-local + 2 shfl_xor.
// PV: B-frag k-slot (g,j): token = 32c + (j<4?0:16) + 4g + (j&3); A = V^T via 2x ds_read_b64.
__global__ __launch_bounds__(256) void flash2(
    const ushort* __restrict__ qhi, const ushort* __restrict__ qlo,
    const ushort* __restrict__ khi, const ushort* __restrict__ klo,
    const ushort* __restrict__ vt, ushort* __restrict__ ctx)
{
  __shared__ ushort smKhi[64 * 72];
  __shared__ ushort smKlo[64 * 72];
  __shared__ ushort smVT[64 * 72];

  const int tid = threadIdx.x;
  const int l = tid & 63;
  const int w = tid >> 6;
  const int x = l & 15;
  const int g = l >> 4;
  const int bh = blockIdx.x;                     // 0..31
  const int qt = (gridDim.y - 1) - blockIdx.y;   // heavy tiles dispatch first
  const int qbase = qt * 128;
  const size_t qkbase = (size_t)bh * S * HD;

  // Q fragments (B-operand): [qset][hi/lo][c]
  bf16x8 bq[2][2][2];
#pragma unroll
  for (int qs = 0; qs < 2; ++qs) {
    int qrow = qbase + w * 32 + qs * 16 + x;
    size_t base = qkbase + (size_t)qrow * HD + g * 8;
    bq[qs][0][0] = *(const bf16x8*)&qhi[base];
    bq[qs][0][1] = *(const bf16x8*)&qhi[base + 32];
    bq[qs][1][0] = *(const bf16x8*)&qlo[base];
    bq[qs][1][1] = *(const bf16x8*)&qlo[base + 32];
  }

  float mrun[2] = {-1e30f, -1e30f};
  float lrun[2] = {0.f, 0.f};
  f32x4 oacc[2][4] = {};   // O^T: d = dt*16+4g+r, q = x

  const int kvmax = (qbase + 127) >> 6;
  const int qmaxw = qbase + w * 32 + 31;
  const float C1 = 0.125f * 1.44269504f;  // fold 1/sqrt(64) into exp2 scale

  for (int kv = 0; kv <= kvmax; ++kv) {
    __syncthreads();
    {
      const ushort* kh  = khi + qkbase + (size_t)kv * 64 * HD;
      const ushort* klp = klo + qkbase + (size_t)kv * 64 * HD;
      const ushort* vtp = vt  + qkbase + (size_t)kv * 64;
#pragma unroll
      for (int p = 0; p < 2; ++p) {
        int rr = p * 32 + (tid >> 3);
        int cc = (tid & 7) * 8;
        *(short8*)&smKhi[rr * 72 + cc] = *(const short8*)&kh[rr * HD + cc];
        *(short8*)&smKlo[rr * 72 + cc] = *(const short8*)&klp[rr * HD + cc];
        *(short8*)&smVT[rr * 72 + cc]  = *(const short8*)&vtp[(size_t)rr * S + cc];
      }
    }
    __syncthreads();
    if (kv * 64 > qmaxw) continue;   // fully masked for this wave (barriers stay aligned)

    // ---- QK^T (swapped): scq[qs][t] = S^T tile, 3-term hi/lo ----
    f32x4 scq[2][4];
#pragma unroll
    for (int t = 0; t < 4; ++t) {
      f32x4 a0 = {}, a1 = {};
#pragma unroll
      for (int c = 0; c < 2; ++c) {
        bf16x8 kH = *(const bf16x8*)&smKhi[(t * 16 + x) * 72 + c * 32 + g * 8];
        bf16x8 kL = *(const bf16x8*)&smKlo[(t * 16 + x) * 72 + c * 32 + g * 8];
        a0 = __builtin_amdgcn_mfma_f32_16x16x32_bf16(kH, bq[0][0][c], a0, 0, 0, 0);
        a0 = __builtin_amdgcn_mfma_f32_16x16x32_bf16(kL, bq[0][0][c], a0, 0, 0, 0);
        a0 = __builtin_amdgcn_mfma_f32_16x16x32_bf16(kH, bq[0][1][c], a0, 0, 0, 0);
        a1 = __builtin_amdgcn_mfma_f32_16x16x32_bf16(kH, bq[1][0][c], a1, 0, 0, 0);
        a1 = __builtin_amdgcn_mfma_f32_16x16x32_bf16(kL, bq[1][0][c], a1, 0, 0, 0);
        a1 = __builtin_amdgcn_mfma_f32_16x16x32_bf16(kH, bq[1][1][c], a1, 0, 0, 0);
      }
      scq[0][t] = a0; scq[1][t] = a1;
    }

    const bool needmask = (kv * 64 + 63 > qbase + w * 32);
    uint32_t pb[2][2][4];

#pragma unroll
    for (int qs = 0; qs < 2; ++qs) {
      if (needmask) {
        int qglob = qbase + w * 32 + qs * 16 + x;
        int kb = kv * 64 + 4 * g;
#pragma unroll
        for (int t = 0; t < 4; ++t)
#pragma unroll
          for (int r = 0; r < 4; ++r)
            if (kb + t * 16 + r > qglob) scq[qs][t][r] = -1e30f;
      }
      // lane-local max over 16, then across the 4 lane-groups sharing q
      float mloc = scq[qs][0][0];
#pragma unroll
      for (int t = 0; t < 4; ++t)
#pragma unroll
        for (int r = 0; r < 4; ++r) mloc = fmaxf(mloc, scq[qs][t][r]);
      mloc = fmaxf(mloc, __shfl_xor(mloc, 16));
      mloc = fmaxf(mloc, __shfl_xor(mloc, 32));
      float mnew = fmaxf(mrun[qs], mloc);
      float mc = mnew * C1;
      float scal = vexp2(mrun[qs] * C1 - mc);
      mrun[qs] = mnew;
      float p[4][4];
      float ps = 0.f;
#pragma unroll
      for (int t = 0; t < 4; ++t)
#pragma unroll
        for (int r = 0; r < 4; ++r) {
          float pv = vexp2(scq[qs][t][r] * C1 - mc);
          p[t][r] = pv; ps += pv;
        }
      ps += __shfl_xor(ps, 16);
      ps += __shfl_xor(ps, 32);
      lrun[qs] = lrun[qs] * scal + ps;
#pragma unroll
      for (int dt = 0; dt < 4; ++dt) oacc[qs][dt] *= scal;
#pragma unroll
      for (int c = 0; c < 2; ++c) {
        pb[qs][c][0] = cvtpk(p[2 * c][0], p[2 * c][1]);
        pb[qs][c][1] = cvtpk(p[2 * c][2], p[2 * c][3]);
        pb[qs][c][2] = cvtpk(p[2 * c + 1][0], p[2 * c + 1][1]);
        pb[qs][c][3] = cvtpk(p[2 * c + 1][2], p[2 * c + 1][3]);
      }
    }

    // ---- PV: O^T += V^T * P ----
#pragma unroll
    for (int c = 0; c < 2; ++c)
#pragma unroll
      for (int dt = 0; dt < 4; ++dt) {
        const ushort* vp = &smVT[(dt * 16 + x) * 72 + c * 32 + 4 * g];
        uint2 vlo = *(const uint2*)vp;
        uint2 vhi = *(const uint2*)(vp + 16);
        bf16x8 vf = pack4(vlo.x, vlo.y, vhi.x, vhi.y);
        oacc[0][dt] = __builtin_amdgcn_mfma_f32_16x16x32_bf16(
            vf, pack4(pb[0][c][0], pb[0][c][1], pb[0][c][2], pb[0][c][3]), oacc[0][dt], 0, 0, 0);
        oacc[1][dt] = __builtin_amdgcn_mfma_f32_16x16x32_bf16(
            vf, pack4(pb[1][c][0], pb[1][c][1], pb[1][c][2], pb[1][c][3]), oacc[1][dt], 0, 0, 0);
      }
  }

  const int b = bh >> 4, h = bh & 15;
#pragma unroll
  for (int qs = 0; qs < 2; ++qs) {
    float inv = 1.0f / lrun[qs];
    int tok = qbase + w * 32 + qs * 16 + x;
#pragma unroll
    for (int dt = 0; dt < 4; ++dt) {
      uint2 uu;
      uu.x = cvtpk(oacc[qs][dt][0] * inv, oacc[qs][dt][1] * inv);
      uu.y = cvtpk(oacc[qs][dt][2] * inv, oacc[qs][dt][3] * inv);
      *(uint2*)&ctx[(size_t)(b * S + tok) * D + h * 64 + dt * 16 + 4 * g] = uu;
    }
  }
}

extern "C" void kernel_launch(void* const* d_in, const int* in_sizes, int n_in,
                              void* d_out, int out_size, void* d_ws, size_t ws_size,
                              hipStream_t stream) {
  const float* x  = (const float*)d_in[0];
  const float* Wq = (const float*)d_in[1];
  const float* Wk = (const float*)d_in[2];
  const float* Wv = (const float*)d_in[3];
  const float* Wo = (const float*)d_in[4];
  const float* bo = (const float*)d_in[5];
  float* out = (float*)d_out;

  if (ws_size < (size_t)120 * 1024 * 1024) return;

  char* ws = (char*)d_ws;
  const size_t MB = 1024 * 1024;
  ushort* xcat = (ushort*)(ws);              // 32MB, later aliased as ctx
  ushort* ctx  = (ushort*)(ws);
  ushort* wqb  = (ushort*)(ws + 32 * MB);
  ushort* wkb  = (ushort*)(ws + 34 * MB);
  ushort* wvb  = (ushort*)(ws + 36 * MB);
  ushort* wob  = (ushort*)(ws + 38 * MB);
  ushort* qhi  = (ushort*)(ws + 40 * MB);
  ushort* qlo  = (ushort*)(ws + 56 * MB);
  ushort* khi  = (ushort*)(ws + 72 * MB);
  ushort* klo  = (ushort*)(ws + 88 * MB);
  ushort* vt   = (ushort*)(ws + 104 * MB);

  prep_x<<<2048, 256, 0, stream>>>(x, xcat);
  prep_w<<<1024, 256, 0, stream>>>(Wq, Wk, Wv, Wo, wqb, wkb, wvb, wob);

  gemm128<0><<<512, 256, 0, stream>>>(xcat, wqb, K2, 1023, qhi, qlo, nullptr, nullptr);
  gemm128<0><<<512, 256, 0, stream>>>(xcat, wkb, K2, 1023, khi, klo, nullptr, nullptr);
  gemm128<1><<<512, 256, 0, stream>>>(xcat, wvb, K2, 1023, vt, nullptr, nullptr, nullptr);

  dim3 fgrid(BATCH * H, S / 128);
  flash2<<<fgrid, 256, 0, stream>>>(qhi, qlo, khi, klo, vt, ctx);

  gemm128<2><<<512, 256, 0, stream>>>(ctx, wob, D, 1023, nullptr, nullptr, out, bo);
}

// Round 3
// 339.894 us; speedup vs baseline: 2.1161x; 1.1820x over previous
//
#include <hip/hip_runtime.h>
#include <hip/hip_bf16.h>
#include <cstdint>
#include <cstddef>

#define S 4096
#define D 1024
#define H 16
#define HD 64
#define BATCH 2
#define M_TOK 8192   // BATCH*S
#define K2 2048

typedef short short8 __attribute__((ext_vector_type(8)));
typedef __bf16 bf16x8 __attribute__((ext_vector_type(8)));
typedef float f32x4 __attribute__((ext_vector_type(4)));
typedef unsigned int u32;

static __device__ __forceinline__ ushort f2bf(float f) {
  union { float f; uint32_t u; } v; v.f = f;
  uint32_t u = v.u + 0x7FFFu + ((v.u >> 16) & 1u);
  return (ushort)(u >> 16);
}
static __device__ __forceinline__ float bf2f(ushort h) {
  union { uint32_t u; float f; } v; v.u = ((uint32_t)h) << 16; return v.f;
}
static __device__ __forceinline__ uint32_t cvtpk(float lo, float hi) {
  uint32_t r;
  asm("v_cvt_pk_bf16_f32 %0, %1, %2" : "=v"(r) : "v"(lo), "v"(hi));
  return r;
}
static __device__ __forceinline__ float vexp2(float x) {
  float r;
  asm("v_exp_f32 %0, %1" : "=v"(r) : "v"(x));
  return r;
}
static __device__ __forceinline__ bf16x8 pack4(uint32_t a, uint32_t b, uint32_t c, uint32_t d) {
  union { uint32_t u[4]; bf16x8 v; } z;
  z.u[0] = a; z.u[1] = b; z.u[2] = c; z.u[3] = d;
  return z.v;
}
// async global->LDS, 16B per lane; LDS dest = wave-uniform base + lane*16
static __device__ __forceinline__ void gld16(const void* g, void* l) {
  __builtin_amdgcn_global_load_lds(
      (const __attribute__((address_space(1))) u32*)g,
      (__attribute__((address_space(3))) u32*)l, 16, 0, 0);
}
static __device__ __forceinline__ ushort sgn(float a) {
  return a > 0.f ? 0x3F80 : (a < 0.f ? 0xBF80 : 0);
}

// ---------------- prep: x -> [hi|lo] bf16 concat (vectorized) ----------------
__global__ void prep_x(const float* __restrict__ x, ushort* __restrict__ xcat) {
  int i = blockIdx.x * blockDim.x + threadIdx.x;
  const int total = M_TOK * 128;   // groups of 8 floats
  for (; i < total; i += gridDim.x * blockDim.x) {
    int row = i >> 7, c8 = (i & 127) * 8;
    const float* px = &x[(size_t)row * 1024 + c8];
    float4 a = *(const float4*)px;
    float4 b = *(const float4*)(px + 4);
    float va[8] = {a.x, a.y, a.z, a.w, b.x, b.y, b.z, b.w};
    union { ushort u[8]; short8 v; } Hh, Ll;
#pragma unroll
    for (int j = 0; j < 8; ++j) {
      ushort h = f2bf(va[j]);
      Hh.u[j] = h;
      Ll.u[j] = f2bf(va[j] - bf2f(h));
    }
    *(short8*)&xcat[(size_t)row * K2 + c8] = Hh.v;
    *(short8*)&xcat[(size_t)row * K2 + 1024 + c8] = Ll.v;
  }
}

// W -> sign(W) bf16; Wq/Wk/Wv concat rows [3072][1024]; Wo separate
__global__ void prep_w(const float* __restrict__ wq, const float* __restrict__ wk,
                       const float* __restrict__ wv, const float* __restrict__ wo,
                       ushort* __restrict__ wcat, ushort* __restrict__ wob) {
  int i = blockIdx.x * blockDim.x + threadIdx.x;
  const int total = (D * D) / 4;
  for (; i < total; i += gridDim.x * blockDim.x) {
    float4 a;
    union { ushort u[4]; uint2 v; } t;
    a = *(const float4*)&wq[i * 4];
    t.u[0] = sgn(a.x); t.u[1] = sgn(a.y); t.u[2] = sgn(a.z); t.u[3] = sgn(a.w);
    *(uint2*)&wcat[i * 4] = t.v;
    a = *(const float4*)&wk[i * 4];
    t.u[0] = sgn(a.x); t.u[1] = sgn(a.y); t.u[2] = sgn(a.z); t.u[3] = sgn(a.w);
    *(uint2*)&wcat[D * D + i * 4] = t.v;
    a = *(const float4*)&wv[i * 4];
    t.u[0] = sgn(a.x); t.u[1] = sgn(a.y); t.u[2] = sgn(a.z); t.u[3] = sgn(a.w);
    *(uint2*)&wcat[2 * D * D + i * 4] = t.v;
    a = *(const float4*)&wo[i * 4];
    t.u[0] = sgn(a.x); t.u[1] = sgn(a.y); t.u[2] = sgn(a.z); t.u[3] = sgn(a.w);
    *(uint2*)&wob[i * 4] = t.v;
  }
}

// ---------------- GEMM (m97 structure): C = A (MxKK) * B^T; B rows wrap at BROW ----------------
// EPI 0: fused QKV epilogue selected by bn>>3 (q/k hi+lo, v transposed+k-slot-permuted).
// EPI 2: fp32 + bias.
template<int EPI, int KK, int BROW>
__global__ __launch_bounds__(256) void gemm97(
    const ushort* __restrict__ A, const ushort* __restrict__ Bw,
    ushort* __restrict__ q_hi, ushort* __restrict__ q_lo,
    ushort* __restrict__ k_hi, ushort* __restrict__ k_lo,
    ushort* __restrict__ v_t,
    float* __restrict__ of, const float* __restrict__ bias)
{
  __shared__ ushort smA[128 * 32];
  __shared__ ushort smB[128 * 32];
  const int tid = threadIdx.x;
  const int l = tid & 63;
  const int w = tid >> 6;
  const int x = l & 15, g = l >> 4;
  const int wm = w >> 1, wn = w & 1;
  const int bm = blockIdx.x, bn = blockIdx.y;

  const ushort* gA[2]; const ushort* gB[2]; int ldso[2];
#pragma unroll
  for (int p = 0; p < 2; ++p) {
    int q = p * 256 + tid;                    // chunk id: row=q>>2, 16B-blk=q&3
    gA[p] = &A[(size_t)(bm * 128 + (q >> 2)) * KK + (q & 3) * 8];
    gB[p] = &Bw[(size_t)(bn * 128 + (q >> 2)) * BROW + (q & 3) * 8];
    ldso[p] = (p * 256 + w * 64) * 8;         // wave-uniform LDS chunk base
  }

  f32x4 acc[4][4] = {};

  for (int k0 = 0; k0 < KK; k0 += 32) {
    __syncthreads();
#pragma unroll
    for (int p = 0; p < 2; ++p) {
      gld16(gA[p] + k0, &smA[ldso[p]]);
      gld16(gB[p] + (k0 & (BROW - 1)), &smB[ldso[p]]);
    }
    __syncthreads();
    bf16x8 af[4], bf_[4];
#pragma unroll
    for (int m = 0; m < 4; ++m)
      af[m] = *(const bf16x8*)&smA[(wm * 64 + m * 16 + x) * 32 + g * 8];
#pragma unroll
    for (int n = 0; n < 4; ++n)
      bf_[n] = *(const bf16x8*)&smB[(wn * 64 + n * 16 + x) * 32 + g * 8];
#pragma unroll
    for (int m = 0; m < 4; ++m)
#pragma unroll
      for (int n = 0; n < 4; ++n)
        acc[m][n] = __builtin_amdgcn_mfma_f32_16x16x32_bf16(af[m], bf_[n], acc[m][n], 0, 0, 0);
  }

  if (EPI == 0) {
    const int proj = bn >> 3;                 // 0=q 1=k 2=v (uniform per block)
    ushort* oh = (proj == 0) ? q_hi : k_hi;
    ushort* ol = (proj == 0) ? q_lo : k_lo;
#pragma unroll
    for (int m = 0; m < 4; ++m)
#pragma unroll
      for (int n = 0; n < 4; ++n)
#pragma unroll
        for (int r = 0; r < 4; ++r) {
          int rowg = bm * 128 + wm * 64 + m * 16 + g * 4 + r;
          int colg = bn * 128 + wn * 64 + n * 16 + x;
          float v = acc[m][n][r];
          int bi = rowg >> 12, ntok = rowg & 4095;
          int cg = colg & 1023;
          int h = cg >> 6, hd = cg & 63;
          size_t bhb = (size_t)(bi * H + h) * (S * HD);
          if (proj < 2) {
            size_t off = bhb + (size_t)ntok * HD + hd;
            ushort hiv = f2bf(v);
            oh[off] = hiv;
            ol[off] = f2bf(v - bf2f(hiv));
          } else {
            // V^T with within-32-token permutation matching MFMA k-slots:
            // token t=16b+4g+r  ->  pos 8g+4b+r
            int t5 = ntok & 31;
            int pos = ((t5 >> 2) & 3) * 8 + ((t5 >> 4) & 1) * 4 + (t5 & 3);
            v_t[bhb + (size_t)hd * S + (ntok & ~31) + pos] = f2bf(v);
          }
        }
  } else {
#pragma unroll
    for (int m = 0; m < 4; ++m)
#pragma unroll
      for (int n = 0; n < 4; ++n)
#pragma unroll
        for (int r = 0; r < 4; ++r) {
          int rowg = bm * 128 + wm * 64 + m * 16 + g * 4 + r;
          int colg = bn * 128 + wn * 64 + n * 16 + x;
          of[(size_t)rowg * D + colg] = acc[m][n][r] + bias[colg];
        }
  }
}

// ---------------- flash v3: gld16-staged XOR-swizzled K/V, defer-max, setprio ----------------
__global__ __launch_bounds__(256) void flash3(
    const ushort* __restrict__ qhi, const ushort* __restrict__ qlo,
    const ushort* __restrict__ khi, const ushort* __restrict__ klo,
    const ushort* __restrict__ vt, ushort* __restrict__ ctx)
{
  __shared__ ushort smKhi[64 * 64];
  __shared__ ushort smKlo[64 * 64];
  __shared__ ushort smVT[64 * 64];

  const int tid = threadIdx.x;
  const int l = tid & 63;
  const int w = tid >> 6;
  const int x = l & 15;
  const int g = l >> 4;
  const int bh = blockIdx.x;
  const int qt = (int)(gridDim.y - 1) - (int)blockIdx.y;   // heavy tiles first
  const int qbase = qt * 128;
  const size_t qkbase = (size_t)bh * S * HD;

  // staging lane constants: chunk q=(row rr, blk); source pre-swizzled so LDS
  // linear position (rr, pb) holds logical blk pb^(rr&7)
  int soff_k[2]; size_t soff_v[2]; int ldso[2];
#pragma unroll
  for (int p = 0; p < 2; ++p) {
    int q = p * 256 + tid;
    int rr = q >> 3;
    int sb = (q & 7) ^ (rr & 7);
    soff_k[p] = rr * HD + sb * 8;
    soff_v[p] = (size_t)rr * S + sb * 8;
    ldso[p] = (p * 256 + w * 64) * 8;
  }

  // Q fragments (B-operand): [qset][hi/lo][c]
  bf16x8 bq[2][2][2];
#pragma unroll
  for (int qs = 0; qs < 2; ++qs) {
    int qrow = qbase + w * 32 + qs * 16 + x;
    size_t base = qkbase + (size_t)qrow * HD + g * 8;
    bq[qs][0][0] = *(const bf16x8*)&qhi[base];
    bq[qs][0][1] = *(const bf16x8*)&qhi[base + 32];
    bq[qs][1][0] = *(const bf16x8*)&qlo[base];
    bq[qs][1][1] = *(const bf16x8*)&qlo[base + 32];
  }

  float mrun[2] = {-1e30f, -1e30f};
  float lrun[2] = {0.f, 0.f};
  f32x4 oacc[2][4] = {};

  const int kvmax = (qbase + 127) >> 6;
  const int qmaxw = qbase + w * 32 + 31;
  const float C1 = 0.125f * 1.44269504f;   // 1/sqrt(64) folded into exp2
  const float TH = 8.0f / C1;              // defer-max threshold (raw score units)

  for (int kv = 0; kv <= kvmax; ++kv) {
    const ushort* kh  = khi + qkbase + (size_t)kv * 64 * HD;
    const ushort* klp = klo + qkbase + (size_t)kv * 64 * HD;
    const ushort* vtp = vt  + qkbase + (size_t)kv * 64;
    __syncthreads();
#pragma unroll
    for (int p = 0; p < 2; ++p) {
      gld16(kh + soff_k[p], &smKhi[ldso[p]]);
      gld16(klp + soff_k[p], &smKlo[ldso[p]]);
      gld16(vtp + soff_v[p], &smVT[ldso[p]]);
    }
    __syncthreads();
    if (kv * 64 > qmaxw) continue;   // fully masked for this wave; barriers stay aligned

    // ---- QK^T (swapped): lane holds S[k=t*16+4g+r][q=x], 3-term hi/lo ----
    f32x4 scq[2][4];
    __builtin_amdgcn_s_setprio(1);
#pragma unroll
    for (int t = 0; t < 4; ++t) {
      f32x4 a0 = {}, a1 = {};
#pragma unroll
      for (int c = 0; c < 2; ++c) {
        int pb = (t * 16 + x) * 64 + ((4 * c + g) ^ (x & 7)) * 8;
        bf16x8 kH = *(const bf16x8*)&smKhi[pb];
        bf16x8 kL = *(const bf16x8*)&smKlo[pb];
        a0 = __builtin_amdgcn_mfma_f32_16x16x32_bf16(kH, bq[0][0][c], a0, 0, 0, 0);
        a0 = __builtin_amdgcn_mfma_f32_16x16x32_bf16(kL, bq[0][0][c], a0, 0, 0, 0);
        a0 = __builtin_amdgcn_mfma_f32_16x16x32_bf16(kH, bq[0][1][c], a0, 0, 0, 0);
        a1 = __builtin_amdgcn_mfma_f32_16x16x32_bf16(kH, bq[1][0][c], a1, 0, 0, 0);
        a1 = __builtin_amdgcn_mfma_f32_16x16x32_bf16(kL, bq[1][0][c], a1, 0, 0, 0);
        a1 = __builtin_amdgcn_mfma_f32_16x16x32_bf16(kH, bq[1][1][c], a1, 0, 0, 0);
      }
      scq[0][t] = a0; scq[1][t] = a1;
    }
    __builtin_amdgcn_s_setprio(0);

    const bool needmask = (kv * 64 + 63 > qbase + w * 32);
    uint32_t pbq[2][2][4];

#pragma unroll
    for (int qs = 0; qs < 2; ++qs) {
      if (needmask) {
        int qglob = qbase + w * 32 + qs * 16 + x;
        int kb = kv * 64 + 4 * g;
#pragma unroll
        for (int t = 0; t < 4; ++t)
#pragma unroll
          for (int r = 0; r < 4; ++r)
            if (kb + t * 16 + r > qglob) scq[qs][t][r] = -1e30f;
      }
      float mloc = scq[qs][0][0];
#pragma unroll
      for (int t = 0; t < 4; ++t)
#pragma unroll
        for (int r = 0; r < 4; ++r) mloc = fmaxf(mloc, scq[qs][t][r]);
      mloc = fmaxf(mloc, __shfl_xor(mloc, 16));
      mloc = fmaxf(mloc, __shfl_xor(mloc, 32));
      // defer-max: only rescale when the running max grew materially (wave-uniform)
      if (!__all(mloc <= mrun[qs] + TH)) {
        float mnew = fmaxf(mrun[qs], mloc);
        float scal = vexp2((mrun[qs] - mnew) * C1);
        mrun[qs] = mnew;
        lrun[qs] *= scal;
#pragma unroll
        for (int dt = 0; dt < 4; ++dt) oacc[qs][dt] *= scal;
      }
      float mc = mrun[qs] * C1;
      float ps = 0.f;
#pragma unroll
      for (int t = 0; t < 4; ++t)
#pragma unroll
        for (int r = 0; r < 4; ++r) {
          float pv = vexp2(scq[qs][t][r] * C1 - mc);
          scq[qs][t][r] = pv;
          ps += pv;
        }
      ps += __shfl_xor(ps, 16);
      ps += __shfl_xor(ps, 32);
      lrun[qs] += ps;
#pragma unroll
      for (int c = 0; c < 2; ++c) {
        pbq[qs][c][0] = cvtpk(scq[qs][2 * c][0], scq[qs][2 * c][1]);
        pbq[qs][c][1] = cvtpk(scq[qs][2 * c][2], scq[qs][2 * c][3]);
        pbq[qs][c][2] = cvtpk(scq[qs][2 * c + 1][0], scq[qs][2 * c + 1][1]);
        pbq[qs][c][3] = cvtpk(scq[qs][2 * c + 1][2], scq[qs][2 * c + 1][3]);
      }
    }

    // ---- PV: O^T += V^T * P ; V pre-permuted so A-frag is one b128 ----
    __builtin_amdgcn_s_setprio(1);
#pragma unroll
    for (int c = 0; c < 2; ++c)
#pragma unroll
      for (int dt = 0; dt < 4; ++dt) {
        bf16x8 vf = *(const bf16x8*)&smVT[(dt * 16 + x) * 64 + ((4 * c + g) ^ (x & 7)) * 8];
        oacc[0][dt] = __builtin_amdgcn_mfma_f32_16x16x32_bf16(
            vf, pack4(pbq[0][c][0], pbq[0][c][1], pbq[0][c][2], pbq[0][c][3]), oacc[0][dt], 0, 0, 0);
        oacc[1][dt] = __builtin_amdgcn_mfma_f32_16x16x32_bf16(
            vf, pack4(pbq[1][c][0], pbq[1][c][1], pbq[1][c][2], pbq[1][c][3]), oacc[1][dt], 0, 0, 0);
      }
    __builtin_amdgcn_s_setprio(0);
  }

  const int b = bh >> 4, h = bh & 15;
#pragma unroll
  for (int qs = 0; qs < 2; ++qs) {
    float inv = 1.0f / lrun[qs];
    int tok = qbase + w * 32 + qs * 16 + x;
#pragma unroll
    for (int dt = 0; dt < 4; ++dt) {
      uint2 uu;
      uu.x = cvtpk(oacc[qs][dt][0] * inv, oacc[qs][dt][1] * inv);
      uu.y = cvtpk(oacc[qs][dt][2] * inv, oacc[qs][dt][3] * inv);
      *(uint2*)&ctx[(size_t)(b * S + tok) * D + h * 64 + dt * 16 + 4 * g] = uu;
    }
  }
}

extern "C" void kernel_launch(void* const* d_in, const int* in_sizes, int n_in,
                              void* d_out, int out_size, void* d_ws, size_t ws_size,
                              hipStream_t stream) {
  const float* x  = (const float*)d_in[0];
  const float* Wq = (const float*)d_in[1];
  const float* Wk = (const float*)d_in[2];
  const float* Wv = (const float*)d_in[3];
  const float* Wo = (const float*)d_in[4];
  const float* bo = (const float*)d_in[5];
  float* out = (float*)d_out;

  if (ws_size < (size_t)120 * 1024 * 1024) return;

  char* ws = (char*)d_ws;
  const size_t MB = 1024 * 1024;
  ushort* xcat = (ushort*)(ws);              // 32MB; ctx aliases (dead after QKV gemm)
  ushort* ctx  = (ushort*)(ws);
  ushort* wcat = (ushort*)(ws + 32 * MB);    // 6MB [3072][1024]
  ushort* wob  = (ushort*)(ws + 38 * MB);    // 2MB
  ushort* qhi  = (ushort*)(ws + 40 * MB);    // 16MB each
  ushort* qlo  = (ushort*)(ws + 56 * MB);
  ushort* khi  = (ushort*)(ws + 72 * MB);
  ushort* klo  = (ushort*)(ws + 88 * MB);
  ushort* vt   = (ushort*)(ws + 104 * MB);

  prep_x<<<2048, 256, 0, stream>>>(x, xcat);
  prep_w<<<1024, 256, 0, stream>>>(Wq, Wk, Wv, Wo, wcat, wob);

  gemm97<0, K2, 1024><<<dim3(64, 24), 256, 0, stream>>>(
      xcat, wcat, qhi, qlo, khi, klo, vt, nullptr, nullptr);

  flash3<<<dim3(BATCH * H, S / 128), 256, 0, stream>>>(qhi, qlo, khi, klo, vt, ctx);

  gemm97<2, 1024, 1024><<<dim3(64, 8), 256, 0, stream>>>(
      ctx, wob, nullptr, nullptr, nullptr, nullptr, nullptr, out, bo);
}